// Round 8
// baseline (569.212 us; speedup 1.0000x reference)
//
#include <hip/hip_runtime.h>

typedef unsigned short u16;
typedef _Float16 f16;
typedef __attribute__((ext_vector_type(8))) _Float16 half8;   // 8 f16 = 4 VGPR
typedef __attribute__((ext_vector_type(4))) _Float16 half4;   // 8 B
typedef __attribute__((ext_vector_type(2))) _Float16 half2v;  // 4 B
typedef __attribute__((ext_vector_type(8))) short short8;     // raw 16B
typedef __attribute__((ext_vector_type(4))) float f32x4;
typedef __attribute__((ext_vector_type(4))) float f4;
typedef __attribute__((ext_vector_type(4))) u16 u16x4;

#define B_ 16
#define S_ 1024
#define DIN_ 1024
#define H_ 16
#define E_ 128

// log2(e) / (E * 0.5): folded into q at the QKV-projection epilogue so the
// attention softmax is exp2(s) with no per-element multiply.
#define EXPK 0.0225546041776533f

__device__ __forceinline__ u16 f2h(float f) {
  f16 h = (f16)f;                         // v_cvt_f16_f32 (RNE)
  return __builtin_bit_cast(u16, h);
}

__device__ __forceinline__ half2v pkrtz(float a, float b) {
  return __builtin_bit_cast(half2v, __builtin_amdgcn_cvt_pkrtz(a, b));
}

__device__ __forceinline__ void gl2lds16(const u16* g, u16* l) {
  // async global->LDS, 16B/lane; LDS dest = wave-uniform base + lane*16
  __builtin_amdgcn_global_load_lds((const __attribute__((address_space(1))) void*)g,
                                   (__attribute__((address_space(3))) void*)l, 16, 0, 0);
}

// ---------------- zero-init fp32 (d_out is poisoned 0xAA) ----------------
__global__ __launch_bounds__(256) void zero_f32(float* __restrict__ p) {
  int i = (blockIdx.x * 256 + threadIdx.x) * 4;
  f4 z = {0.f, 0.f, 0.f, 0.f};
  *reinterpret_cast<f4*>(p + i) = z;
}

// ---------------- elementwise fp32 -> fp16 ----------------
__global__ __launch_bounds__(256) void cvt_f32_f16(const float* __restrict__ in,
                                                   u16* __restrict__ out) {
  int i = (blockIdx.x * 256 + threadIdx.x) * 4;
  f4 v = *reinterpret_cast<const f4*>(in + i);
  u16x4 o;
  o[0] = f2h(v[0]); o[1] = f2h(v[1]); o[2] = f2h(v[2]); o[3] = f2h(v[3]);
  *reinterpret_cast<u16x4*>(out + i) = o;
}

// ---------------- batched [R][C] fp32 -> [C][R] fp16 transpose ----------------
__global__ __launch_bounds__(256) void transpose_cvt(const float* __restrict__ in,
                                                     u16* __restrict__ out,
                                                     int R, int C) {
  __shared__ float tile[32][33];
  const size_t moff = (size_t)blockIdx.z * R * C;
  const float* src = in + moff;
  u16* dst = out + moff;
  int c0 = blockIdx.x * 32, r0 = blockIdx.y * 32;
  int tx = threadIdx.x & 31, ty = threadIdx.x >> 5;  // 32 x 8
#pragma unroll
  for (int i = 0; i < 32; i += 8)
    tile[ty + i][tx] = src[(size_t)(r0 + ty + i) * C + c0 + tx];
  __syncthreads();
#pragma unroll
  for (int i = 0; i < 32; i += 8)
    dst[(size_t)(c0 + ty + i) * R + r0 + tx] = f2h(tile[tx][ty + i]);
}

// ---------------- 128x128-tile fp16 GEMM, BK=64, B transposed (BT[n][k]) -----
// global_load_lds(16B) staging into chunk-swizzled unpadded LDS; K templated
// so the K-loop fully unrolls (R6: addresses fold to immediates).
// MODE 0: C -> q (scaled by EXPK) / k / vT (via LDS transpose) per blockIdx.y%3
// MODE 1 (KSPLIT>1): atomicAdd fp32 into pre-zeroed out [M][128]
template<int MODE, int KSPLIT, int K>
__global__ __launch_bounds__(256) void gemm_bt(const u16* __restrict__ A,
                                               const u16* __restrict__ BT,
                                               u16* __restrict__ q, u16* __restrict__ kk,
                                               u16* __restrict__ vT, float* __restrict__ out) {
  const int tid = threadIdx.x;
  const int m0 = blockIdx.x * 128;
  const u16* Bblk = BT + (size_t)blockIdx.y * 128 * K;
  __shared__ __align__(16) u16 smem[132 * 128];   // 33,792 B (also vT transpose buf)
  u16* As = smem;            // [128][64] chunk-swizzled, 8192 u16
  u16* Bs = smem + 8192;
  const int w = tid >> 6, lane = tid & 63;
  const int quad = lane >> 4, ln = lane & 15;
  const int wr = w >> 1, wc = w & 1;

  const int kbeg = (KSPLIT > 1) ? blockIdx.z * (K / KSPLIT) : 0;
  constexpr int KLEN = K / KSPLIT;

  // staging: issue i, wave w, lane -> chunk L = i*256 + w*64 + lane
  const int rr = lane >> 3;             // row&7 (i*32, w*8 are 0 mod 8)
  const int cc = (lane & 7) ^ rr;       // global chunk col for this lane
  const u16* agp[4];
  const u16* bgp[4];
#pragma unroll
  for (int i = 0; i < 4; i++) {
    int row = i * 32 + w * 8 + rr;
    agp[i] = A + (size_t)(m0 + row) * K + kbeg + cc * 8;
    bgp[i] = Bblk + (size_t)row * K + kbeg + cc * 8;
  }

  // fragment read offsets: row = ...*16 + ln (row&7 = ln&7), k-chunk c = k2*4+quad
  int offA[4][2], offB[4][2];
#pragma unroll
  for (int mt = 0; mt < 4; mt++) {
    int row = wr * 64 + mt * 16 + ln;
#pragma unroll
    for (int k2 = 0; k2 < 2; k2++)
      offA[mt][k2] = row * 64 + (((k2 * 4 + quad) ^ (ln & 7)) * 8);
  }
#pragma unroll
  for (int nt = 0; nt < 4; nt++) {
    int row = wc * 64 + nt * 16 + ln;
#pragma unroll
    for (int k2 = 0; k2 < 2; k2++)
      offB[nt][k2] = row * 64 + (((k2 * 4 + quad) ^ (ln & 7)) * 8);
  }

  f32x4 acc[4][4];
  f32x4 zero = {0.f, 0.f, 0.f, 0.f};
#pragma unroll
  for (int mt = 0; mt < 4; mt++)
#pragma unroll
    for (int nt = 0; nt < 4; nt++) acc[mt][nt] = zero;

#pragma unroll
  for (int k0 = 0; k0 < KLEN; k0 += 64) {
    __syncthreads();                 // previous iter's fragment reads done
#pragma unroll
    for (int i = 0; i < 4; i++) {
      gl2lds16(agp[i] + k0, As + i * 2048 + w * 512);
      gl2lds16(bgp[i] + k0, Bs + i * 2048 + w * 512);
    }
    __syncthreads();                 // vmcnt drain -> tile visible
#pragma unroll
    for (int k2 = 0; k2 < 2; k2++) {
      half8 af[4], bfr[4];
#pragma unroll
      for (int mt = 0; mt < 4; mt++)
        af[mt] = *reinterpret_cast<const half8*>(&As[offA[mt][k2]]);
#pragma unroll
      for (int nt = 0; nt < 4; nt++)
        bfr[nt] = *reinterpret_cast<const half8*>(&Bs[offB[nt][k2]]);
#pragma unroll
      for (int mt = 0; mt < 4; mt++)
#pragma unroll
        for (int nt = 0; nt < 4; nt++)
          acc[mt][nt] = __builtin_amdgcn_mfma_f32_16x16x32_f16(af[mt], bfr[nt], acc[mt][nt], 0, 0, 0);
    }
  }

  if (MODE == 0) {
    const int h = blockIdx.y / 3, c = blockIdx.y % 3;
    if (c < 2) {
      u16* dst = (c == 0) ? q : kk;
      const float sc = (c == 0) ? EXPK : 1.0f;  // fold softmax scale into q
#pragma unroll
      for (int mt = 0; mt < 4; mt++)
#pragma unroll
        for (int nt = 0; nt < 4; nt++)
#pragma unroll
          for (int r = 0; r < 4; r++) {
            int row = wr * 64 + mt * 16 + quad * 4 + r;  // C/D: row=quad*4+reg
            int tok = m0 + row;
            int bb = tok >> 10, s = tok & 1023;          // local batch idx
            int e = wc * 64 + nt * 16 + ln;              // C/D: col=lane&15
            dst[(((size_t)bb * H_ + h) * S_ + s) * E_ + e] = f2h(acc[mt][nt][r] * sc);
          }
    } else {
      // vT: transpose tile through LDS -> coalesced stores along s
      __syncthreads();   // done with As/Bs fragment reads
#pragma unroll
      for (int mt = 0; mt < 4; mt++)
#pragma unroll
        for (int nt = 0; nt < 4; nt++)
#pragma unroll
          for (int r = 0; r < 4; r++) {
            int row = wr * 64 + mt * 16 + quad * 4 + r;
            int e = wc * 64 + nt * 16 + ln;
            smem[e * 132 + row] = f2h(acc[mt][nt][r]);  // stride 132: 2-way banks, free
          }
      __syncthreads();
      const int bb = m0 >> 10, sbase = m0 & 1023;
      u16* vbase = vT + (((size_t)bb * H_ + h) * E_) * S_;
#pragma unroll
      for (int i = 0; i < 8; i++) {
        int e = (tid >> 4) + i * 16, s0 = (tid & 15) * 8;
        *reinterpret_cast<short8*>(&vbase[(size_t)e * S_ + sbase + s0]) =
            *reinterpret_cast<const short8*>(&smem[e * 132 + s0]);
      }
    }
  } else {
#pragma unroll
    for (int mt = 0; mt < 4; mt++)
#pragma unroll
      for (int nt = 0; nt < 4; nt++)
#pragma unroll
        for (int r = 0; r < 4; r++) {
          int row = wr * 64 + mt * 16 + quad * 4 + r;
          int e = wc * 64 + nt * 16 + ln;
          if (KSPLIT > 1)
            atomicAdd(&out[(size_t)(m0 + row) * E_ + e], acc[mt][nt][r]);
          else
            out[(size_t)(m0 + row) * E_ + e] = acc[mt][nt][r];
        }
  }
}

// ---------------- flash attention, transpose-free P path ----------------
// S^T = MFMA(A=K, B=Q): C-layout gives lane (quad,ln): qrow=ln, keys=quad*4+r
// -> exactly the PV A-fragment rows. K-dim permutation freedom: with
// pi(kpos=q*8+j) = (j>=4 ? 16 : 0) + q*4 + (j&3) applied to BOTH P (A) and
// V (B) operands, the P fragment is built lane-locally from 2 cvt_pkrtz packs
// (NO LDS round-trip, NO cross-lane exchange). V side of pi = 2x ds_read_b64
// per fragment from the existing swizzled vs layout (2-way banks = free).
struct SmemKV {
  u16 ks[64 * 128];   // K tile [key][e],  chunk-swizzled c^=row&7 (16 chunks/row)
  u16 vs[128 * 64];   // V^T tile [e][key], chunk-swizzled c^=row&7 (8 chunks/row)
};
union SmemAttn {
  u16 qs[128 * 132];  // Q tile [128][128] pad->132
  SmemKV s;
};

__global__ __launch_bounds__(256, 3) void attn_kernel(const u16* __restrict__ qg,
                                                      const u16* __restrict__ kg,
                                                      const u16* __restrict__ vg,
                                                      u16* __restrict__ og) {
  __shared__ __align__(16) SmemAttn sm;
  const int tid = threadIdx.x;
  // id = g*64 + qt*8 + x ; hb = g*8 + x ; all qt of one hb share id%8 (XCD)
  const int id = blockIdx.x;
  const int g = id >> 6, qt = (id >> 3) & 7, x = id & 7;
  const int hb = g * 8 + x;
  const int b = hb >> 4, h = hb & 15;
  const int q0 = qt * 128;
  const size_t bh = (size_t)(b * H_ + h);
  const u16* qp = qg + bh * S_ * E_;
  const u16* kp = kg + bh * S_ * E_;
  const u16* vp = vg + bh * E_ * S_;  // [e][s]
  const int w = tid >> 6, lane = tid & 63, quad = lane >> 4, ln = lane & 15;

  // stage Q tile, pull this wave's B-fragments into registers
#pragma unroll
  for (int i = 0; i < 8; i++) {
    int idx = tid + i * 256;
    int row = idx >> 4, col = (idx & 15) * 8;
    *reinterpret_cast<short8*>(&sm.qs[row * 132 + col]) =
        *reinterpret_cast<const short8*>(&qp[(size_t)(q0 + row) * E_ + col]);
  }
  __syncthreads();
  half8 qf[2][4];
#pragma unroll
  for (int mt = 0; mt < 2; mt++)
#pragma unroll
    for (int ks = 0; ks < 4; ks++)
      qf[mt][ks] = *reinterpret_cast<const half8*>(
          &sm.qs[(w * 32 + mt * 16 + ln) * 132 + ks * 32 + quad * 8]);

  // K staging geometry: chunk L = i*256 + w*64 + lane; row = L>>4; c' = L&15;
  // global c = (c'&8) | ((c'&7) ^ (row&7)); row&7 is i-invariant.
  const int krow = w * 4 + (lane >> 4);                       // + i*16
  const int kc = ((lane & 15) & 8) | (((lane & 15) & 7) ^ (krow & 7));
  const u16* kbase = kp + (size_t)krow * E_ + kc * 8;         // + kt*8192 + i*16*E_
  // V staging: chunk L = i*256 + w*64 + lane; row = L>>3; c' = L&7; c = c'^(row&7)
  const int vrow = w * 8 + (lane >> 3);                       // + i*32
  const int vc = (lane & 7) ^ ((lane >> 3) & 7);
  const u16* vbase = vp + (size_t)vrow * S_ + vc * 8;         // + kt*64 + i*32*S_

  f32x4 zero = {0.f, 0.f, 0.f, 0.f};
  f32x4 oa[2][8];   // O[qrow-tile mt][e-tile nt8], C-layout row=qrow, col=e
#pragma unroll
  for (int mt = 0; mt < 2; mt++)
#pragma unroll
    for (int nt = 0; nt < 8; nt++) oa[mt][nt] = zero;
  float lsum[2] = {0.f, 0.f};  // per qrow = {w*32, w*32+16} + ln (partial: own quad's keys)

  const int xr = ln & 7, qh = quad >> 1, ql4 = (quad & 1) * 4;

  for (int kt = 0; kt < 16; kt++) {
    __syncthreads();  // previous compute done with ks/vs
#pragma unroll
    for (int i = 0; i < 4; i++) {
      gl2lds16(kbase + (size_t)kt * 8192 + i * 16 * E_, &sm.s.ks[(i * 256 + w * 64) * 8]);
      gl2lds16(vbase + (size_t)kt * 64 + i * 32 * S_,   &sm.s.vs[(i * 256 + w * 64) * 8]);
    }
    __syncthreads();  // vmcnt drain -> tiles visible

    // S^T = K Q^T (wave: 64 keys x 32 q-rows): sa[t][nt], key=t*16+quad*4+r, qrow=nt*16+ln
    f32x4 sa[4][2];
#pragma unroll
    for (int t = 0; t < 4; t++)
#pragma unroll
      for (int nt = 0; nt < 2; nt++) sa[t][nt] = zero;
#pragma unroll
    for (int ks = 0; ks < 4; ks++) {
      half8 kf[4];
#pragma unroll
      for (int t = 0; t < 4; t++) {
        int c = ks * 4 + quad;
        int cs = (c & 8) | ((c & 7) ^ xr);
        kf[t] = *reinterpret_cast<const half8*>(&sm.s.ks[(t * 16 + ln) * 128 + cs * 8]);
      }
#pragma unroll
      for (int t = 0; t < 4; t++)
#pragma unroll
        for (int nt = 0; nt < 2; nt++)
          sa[t][nt] = __builtin_amdgcn_mfma_f32_16x16x32_f16(kf[t], qf[nt][ks], sa[t][nt], 0, 0, 0);
    }

    // p = exp2(s) (scale folded into q); pack lane-local into half2 pairs
    half2v pk[4][2][2];
#pragma unroll
    for (int t = 0; t < 4; t++)
#pragma unroll
      for (int nt = 0; nt < 2; nt++) {
        float p0 = exp2f(sa[t][nt][0]), p1 = exp2f(sa[t][nt][1]);
        float p2 = exp2f(sa[t][nt][2]), p3 = exp2f(sa[t][nt][3]);
        lsum[nt] += (p0 + p1) + (p2 + p3);
        pk[t][nt][0] = pkrtz(p0, p1);
        pk[t][nt][1] = pkrtz(p2, p3);
      }

    // O += P V with permuted K-dim: A=pf (lane-local), B=vf (2x ds_read_b64)
#pragma unroll
    for (int c2 = 0; c2 < 2; c2++) {
      half8 pf[2];
#pragma unroll
      for (int mt = 0; mt < 2; mt++) {
        union { half8 v8; half2v v2[4]; } u;
        u.v2[0] = pk[2 * c2][mt][0];
        u.v2[1] = pk[2 * c2][mt][1];
        u.v2[2] = pk[2 * c2 + 1][mt][0];
        u.v2[3] = pk[2 * c2 + 1][mt][1];
        pf[mt] = u.v8;
      }
      const int s1 = ((4 * c2 + qh) ^ xr) * 8 + ql4;
      const int s2 = ((4 * c2 + 2 + qh) ^ xr) * 8 + ql4;
#pragma unroll
      for (int nt8 = 0; nt8 < 8; nt8++) {
        int rowoff = (nt8 * 16 + ln) * 64;
        union { half8 v8; half4 h4[2]; } vv;
        vv.h4[0] = *reinterpret_cast<const half4*>(&sm.s.vs[rowoff + s1]);
        vv.h4[1] = *reinterpret_cast<const half4*>(&sm.s.vs[rowoff + s2]);
#pragma unroll
        for (int mt = 0; mt < 2; mt++)
          oa[mt][nt8] = __builtin_amdgcn_mfma_f32_16x16x32_f16(pf[mt], vv.v8, oa[mt][nt8], 0, 0, 0);
      }
    }
  }

  // epilogue: total l per qrow = sum over the 4 quads (disjoint keys)
  float rl[2];
#pragma unroll
  for (int nt = 0; nt < 2; nt++) {
    float l = lsum[nt];
    l += __shfl_xor(l, 16);
    l += __shfl_xor(l, 32);
    rl[nt] = 1.0f / l;   // for qrow = w*32 + nt*16 + ln (quad-uniform)
  }
  // redistribute: oa rows are qrow = mt*16 + quad*4 + r -> fetch rl from lane ln=quad*4+r
#pragma unroll
  for (int mt = 0; mt < 2; mt++) {
#pragma unroll
    for (int r = 0; r < 4; r++) {
      int src = (lane & 48) | (quad * 4 + r);
      float rlx = __shfl(rl[mt], src);
      int srow = q0 + w * 32 + mt * 16 + quad * 4 + r;
      size_t base = ((size_t)b * S_ + srow) * (H_ * E_) + (size_t)h * E_;
#pragma unroll
      for (int nt8 = 0; nt8 < 8; nt8++)
        og[base + nt8 * 16 + ln] = f2h(oa[mt][nt8][r] * rlx);
    }
  }
}

// ---------------- launch ----------------
extern "C" void kernel_launch(void* const* d_in, const int* in_sizes, int n_in,
                              void* d_out, int out_size, void* d_ws, size_t ws_size,
                              hipStream_t stream) {
  const float* x = (const float*)d_in[0];    // [16,1024,1024]
  const float* W = (const float*)d_in[1];    // [16,3,1024,128]
  const float* Wo = (const float*)d_in[2];   // [2048,128]
  float* out = (float*)d_out;                // [16,1024,128] fp32
  char* ws = (char*)d_ws;

  const size_t WBT_BYTES = (size_t)H_ * 3 * DIN_ * E_ * 2;   // 12,582,912
  const size_t WOT_BYTES = (size_t)H_ * E_ * E_ * 2 * 2;     //    524,288
  const size_t FIXED = WBT_BYTES + WOT_BYTES;

  const size_t XB_PER   = (size_t)S_ * DIN_ * 2;
  const size_t QKV_PER  = (size_t)H_ * S_ * E_ * 2;
  const size_t OB_PER   = (size_t)S_ * H_ * E_ * 2;
  const size_t PER_ITEM = XB_PER + 3 * QKV_PER + OB_PER;     // 18,874,368

  int Bc = 1;
  for (int c = 16; c >= 1; c >>= 1) {
    if (FIXED + (size_t)c * PER_ITEM <= ws_size) { Bc = c; break; }
  }

  u16* WbT = (u16*)(ws);
  u16* WoT = (u16*)(ws + WBT_BYTES);
  char* cb = ws + FIXED;
  u16* xb  = (u16*)(cb);
  u16* qb  = (u16*)(cb + (size_t)Bc * XB_PER);
  u16* kb  = (u16*)(cb + (size_t)Bc * (XB_PER + QKV_PER));
  u16* vTb = (u16*)(cb + (size_t)Bc * (XB_PER + 2 * QKV_PER));
  u16* ob  = (u16*)(cb + (size_t)Bc * (XB_PER + 3 * QKV_PER));

  zero_f32<<<out_size / 1024, 256, 0, stream>>>(out);  // split-K outproj accumulates
  transpose_cvt<<<dim3(4, 32, 48), 256, 0, stream>>>(W, WbT, DIN_, E_);
  transpose_cvt<<<dim3(4, 64, 1), 256, 0, stream>>>(Wo, WoT, H_ * E_, E_);

  for (int b0 = 0; b0 < B_; b0 += Bc) {
    const float* xc = x + (size_t)b0 * S_ * DIN_;
    cvt_f32_f16<<<Bc * S_ * DIN_ / 1024, 256, 0, stream>>>(xc, xb);
    gemm_bt<0, 1, DIN_><<<dim3(Bc * 8, 48), 256, 0, stream>>>(xb, WbT, qb, kb, vTb, nullptr);
    attn_kernel<<<Bc * 128, 256, 0, stream>>>(qb, kb, vTb, ob);
    gemm_bt<1, 4, H_ * E_><<<dim3(Bc * 8, 1, 4), 256, 0, stream>>>(ob, WoT, nullptr, nullptr,
                                                                   nullptr, out + (size_t)b0 * S_ * E_);
  }
}